// Round 2
// baseline (4519.830 us; speedup 1.0000x reference)
//
#include <hip/hip_runtime.h>
#include <cstdint>
#include <cstddef>

#define NN 16384
#define IND 1024
#define HD 256
#define KNN 5

// ===================== GEMM: C = op(A@B [+bias][*rowscale[m]]) =====================
// 64x128 tile, 4x8 micro, 256 threads. A:MxK row-major, B:KxN row-major.
template<bool RELU, bool BIAS, bool RS>
__global__ __launch_bounds__(256) void gemm_4x8(
    const float* __restrict__ A, const float* __restrict__ B,
    const float* __restrict__ bias, const float* __restrict__ rowscale,
    float* __restrict__ C, int M, int Nc, int K)
{
  __shared__ float As[16][68];   // [k][m], row stride 68 floats = 272B (16B aligned)
  __shared__ float Bs[16][132];  // [k][n]
  const int tid = threadIdx.x;
  const int tx = tid & 15, ty = tid >> 4;
  const int m0 = blockIdx.x * 64, n0 = blockIdx.y * 128;

  float acc[4][8];
  #pragma unroll
  for (int i = 0; i < 4; ++i)
    #pragma unroll
    for (int j = 0; j < 8; ++j) acc[i][j] = 0.0f;

  const int am  = tid >> 2;        // 0..63
  const int akq = (tid & 3) * 4;   // 0,4,8,12

  for (int kb = 0; kb < K; kb += 16) {
    {
      float4 v = *(const float4*)&A[(size_t)(m0 + am) * K + kb + akq];
      As[akq + 0][am] = v.x; As[akq + 1][am] = v.y;
      As[akq + 2][am] = v.z; As[akq + 3][am] = v.w;
    }
    #pragma unroll
    for (int c = 0; c < 2; ++c) {
      int idx = tid + c * 256;     // 0..511
      int k = idx >> 5;            // 0..15
      int f = idx & 31;            // 0..31
      float4 v = *(const float4*)&B[(size_t)(kb + k) * Nc + n0 + f * 4];
      *(float4*)&Bs[k][f * 4] = v;
    }
    __syncthreads();
    #pragma unroll
    for (int k = 0; k < 16; ++k) {
      float a[4], b[8];
      *(float4*)&a[0] = *(const float4*)&As[k][ty * 4];
      // split columns (tx*4 and 64+tx*4) keeps b128 LDS reads 2-way (free) not 4-way
      *(float4*)&b[0] = *(const float4*)&Bs[k][tx * 4];
      *(float4*)&b[4] = *(const float4*)&Bs[k][64 + tx * 4];
      #pragma unroll
      for (int i = 0; i < 4; ++i)
        #pragma unroll
        for (int j = 0; j < 8; ++j)
          acc[i][j] = fmaf(a[i], b[j], acc[i][j]);
    }
    __syncthreads();
  }

  float bvals[8];
  if (BIAS) {
    *(float4*)&bvals[0] = *(const float4*)&bias[n0 + tx * 4];
    *(float4*)&bvals[4] = *(const float4*)&bias[n0 + 64 + tx * 4];
  }
  #pragma unroll
  for (int i = 0; i < 4; ++i) {
    int m = m0 + ty * 4 + i;
    float rs = RS ? rowscale[m] : 1.0f;
    float o[8];
    #pragma unroll
    for (int j = 0; j < 8; ++j) {
      float v = acc[i][j];
      if (BIAS) v += bvals[j];
      if (RS) v *= rs;
      if (RELU) v = fmaxf(v, 0.0f);
      o[j] = v;
    }
    *(float4*)&C[(size_t)m * Nc + n0 + tx * 4]      = *(float4*)&o[0];
    *(float4*)&C[(size_t)m * Nc + n0 + 64 + tx * 4] = *(float4*)&o[4];
  }
}

// ===================== row squared norms =====================
__global__ __launch_bounds__(256) void sq_kernel(const float* __restrict__ h, float* __restrict__ sq)
{
  const int w = threadIdx.x >> 6, l = threadIdx.x & 63;
  const int r = blockIdx.x * 4 + w;
  float4 v = *(const float4*)&h[(size_t)r * HD + l * 4];
  float s = v.x * v.x + v.y * v.y + v.z * v.z + v.w * v.w;
  #pragma unroll
  for (int o = 32; o; o >>= 1) s += __shfl_down(s, o);
  if (l == 0) sq[r] = s;
}

// ===================== fused pairwise-distance + top-5 =====================
// Block owns 64 rows (panel resident in LDS), streams 128-wide j tiles.
// Rank by d = sq[j] - 2*h[i].h[j]  (sq[i] constant per row, irrelevant to top-k).
// Per-thread top-5 in registers (static insertion ladder), 16-way merge per row at end.
// Tie-break matches jax.lax.top_k: equal value -> lower index.
__global__ __launch_bounds__(256) void dist_topk(
    const float* __restrict__ h, const float* __restrict__ sq, int* __restrict__ nbr)
{
  __shared__ float Ah[HD][68];   // [k][r] transposed panel, 69632 B
  __shared__ float Bs[16][132];  // [k][n] 8448 B
  const int tid = threadIdx.x;
  const int tx = tid & 15, ty = tid >> 4;
  const int rbase = blockIdx.x * 64;

  #pragma unroll
  for (int c = 0; c < 16; ++c) {
    int idx = tid + c * 256;     // 0..4095
    int r  = idx >> 6;           // 0..63
    int f4 = idx & 63;           // 0..63
    float4 v = *(const float4*)&h[(size_t)(rbase + r) * HD + f4 * 4];
    Ah[f4 * 4 + 0][r] = v.x; Ah[f4 * 4 + 1][r] = v.y;
    Ah[f4 * 4 + 2][r] = v.z; Ah[f4 * 4 + 3][r] = v.w;
  }

  float bv[4][5]; int bi[4][5];
  #pragma unroll
  for (int i = 0; i < 4; ++i)
    #pragma unroll
    for (int s = 0; s < 5; ++s) { bv[i][s] = 3.0e38f; bi[i][s] = 0; }

  __syncthreads();

  for (int j0 = 0; j0 < NN; j0 += 128) {
    float acc[4][8];
    #pragma unroll
    for (int i = 0; i < 4; ++i)
      #pragma unroll
      for (int j = 0; j < 8; ++j) acc[i][j] = 0.0f;

    for (int kb = 0; kb < HD; kb += 16) {
      #pragma unroll
      for (int c = 0; c < 2; ++c) {
        int idx = tid + c * 256;   // 0..511
        int n  = idx >> 2;         // 0..127
        int kq = (idx & 3) * 4;    // 0,4,8,12
        float4 v = *(const float4*)&h[(size_t)(j0 + n) * HD + kb + kq];
        Bs[kq + 0][n] = v.x; Bs[kq + 1][n] = v.y;
        Bs[kq + 2][n] = v.z; Bs[kq + 3][n] = v.w;
      }
      __syncthreads();
      #pragma unroll
      for (int k = 0; k < 16; ++k) {
        float a[4], b[8];
        *(float4*)&a[0] = *(const float4*)&Ah[kb + k][ty * 4];
        *(float4*)&b[0] = *(const float4*)&Bs[k][tx * 4];
        *(float4*)&b[4] = *(const float4*)&Bs[k][64 + tx * 4];
        #pragma unroll
        for (int i = 0; i < 4; ++i)
          #pragma unroll
          for (int j = 0; j < 8; ++j)
            acc[i][j] = fmaf(a[i], b[j], acc[i][j]);
      }
      __syncthreads();
    }

    float4 s0 = *(const float4*)&sq[j0 + tx * 4];
    float4 s1 = *(const float4*)&sq[j0 + 64 + tx * 4];
    float sqv[8] = { s0.x, s0.y, s0.z, s0.w, s1.x, s1.y, s1.z, s1.w };

    #pragma unroll
    for (int i = 0; i < 4; ++i) {
      const int irow = rbase + ty * 4 + i;
      #pragma unroll
      for (int j = 0; j < 8; ++j) {
        const int jcol = j0 + ((j < 4) ? (tx * 4 + j) : (64 + tx * 4 + (j - 4)));
        float d = sqv[j] - 2.0f * acc[i][j];
        if (jcol != irow && d < bv[i][4]) {   // strict < : earlier index wins ties
          if (d < bv[i][0]) {
            bv[i][4]=bv[i][3]; bi[i][4]=bi[i][3];
            bv[i][3]=bv[i][2]; bi[i][3]=bi[i][2];
            bv[i][2]=bv[i][1]; bi[i][2]=bi[i][1];
            bv[i][1]=bv[i][0]; bi[i][1]=bi[i][0];
            bv[i][0]=d; bi[i][0]=jcol;
          } else if (d < bv[i][1]) {
            bv[i][4]=bv[i][3]; bi[i][4]=bi[i][3];
            bv[i][3]=bv[i][2]; bi[i][3]=bi[i][2];
            bv[i][2]=bv[i][1]; bi[i][2]=bi[i][1];
            bv[i][1]=d; bi[i][1]=jcol;
          } else if (d < bv[i][2]) {
            bv[i][4]=bv[i][3]; bi[i][4]=bi[i][3];
            bv[i][3]=bv[i][2]; bi[i][3]=bi[i][2];
            bv[i][2]=d; bi[i][2]=jcol;
          } else if (d < bv[i][3]) {
            bv[i][4]=bv[i][3]; bi[i][4]=bi[i][3];
            bv[i][3]=d; bi[i][3]=jcol;
          } else {
            bv[i][4]=d; bi[i][4]=jcol;
          }
        }
      }
    }
  }

  // merge 16 partial top-5s per row (reuse Ah LDS: 64 rows x 176 floats)
  __syncthreads();
  float* M = &Ah[0][0];
  #pragma unroll
  for (int i = 0; i < 4; ++i) {
    int r = ty * 4 + i;
    #pragma unroll
    for (int s = 0; s < 5; ++s) {
      M[r * 176 + tx * 5 + s]      = bv[i][s];
      M[r * 176 + 88 + tx * 5 + s] = __int_as_float(bi[i][s]);
    }
  }
  __syncthreads();
  if (tid < 64) {
    const int irow = rbase + tid;
    #pragma unroll 1
    for (int s = 0; s < KNN; ++s) {
      float bestv = 3.0e38f; int bestid = 0x7fffffff; int bestt = 0;
      #pragma unroll 1
      for (int t = 0; t < 80; ++t) {
        float v = M[tid * 176 + t];
        int id = __float_as_int(M[tid * 176 + 88 + t]);
        if (v < bestv || (v == bestv && id < bestid)) { bestv = v; bestid = id; bestt = t; }
      }
      M[tid * 176 + bestt] = 3.0e38f;
      nbr[irow * KNN + s] = bestid;
    }
  }
}

// ===================== graph build =====================
__global__ void count_kernel(const int* __restrict__ nbr, int* __restrict__ cnt)
{
  int e = blockIdx.x * 256 + threadIdx.x;
  if (e < NN * KNN) atomicAdd(&cnt[nbr[e]], 1);
}

__global__ void dinv_kernel(const int* __restrict__ cnt, float* __restrict__ dinv)
{
  int i = blockIdx.x * 256 + threadIdx.x;
  if (i < NN) dinv[i] = 1.0f / sqrtf((float)(cnt[i] + KNN + 1));  // deg = indeg + K + 1
}

__global__ __launch_bounds__(256) void scan_kernel(const int* __restrict__ cnt, int* __restrict__ off)
{
  __shared__ int ps[256];
  const int t = threadIdx.x;
  int s = 0;
  for (int i = 0; i < 64; ++i) s += cnt[t * 64 + i];
  ps[t] = s;
  __syncthreads();
  if (t == 0) {
    int run = 0;
    for (int q = 0; q < 256; ++q) { int v = ps[q]; ps[q] = run; run += v; }
  }
  __syncthreads();
  int base = ps[t];
  for (int i = 0; i < 64; ++i) { off[t * 64 + i] = base; base += cnt[t * 64 + i]; }
}

__global__ void fill_rev(const int* __restrict__ nbr, const int* __restrict__ off,
                         int* __restrict__ cur, int* __restrict__ rev)
{
  int e = blockIdx.x * 256 + threadIdx.x;
  if (e < NN * KNN) {
    int i = e / KNN;
    int c = nbr[e];
    int s = atomicAdd(&cur[c], 1);
    rev[off[c] + s] = i;
  }
}

// ===================== GCN aggregation (pure gather via reverse CSR) =====================
// out[c] = relu?( dinv[c] * ( g[c] + sum_k g[nbr[c][k]] + sum_{rev in-edges} g[r] ) + bias )
__global__ __launch_bounds__(64) void aggregate(
    const float* __restrict__ g, const int* __restrict__ nbr,
    const int* __restrict__ rev, const int* __restrict__ off, const int* __restrict__ cnt,
    const float* __restrict__ dinv, const float* __restrict__ bias,
    float* __restrict__ out, int do_relu)
{
  const int c = blockIdx.x;
  const int l = threadIdx.x;
  const float4* g4 = (const float4*)g;
  float4 v = g4[(size_t)c * (HD / 4) + l];
  float ax = v.x, ay = v.y, az = v.z, aw = v.w;
  #pragma unroll
  for (int k = 0; k < KNN; ++k) {
    int r = nbr[c * KNN + k];
    float4 u = g4[(size_t)r * (HD / 4) + l];
    ax += u.x; ay += u.y; az += u.z; aw += u.w;
  }
  const int o0 = off[c], o1 = o0 + cnt[c];
  for (int j = o0; j < o1; ++j) {
    int r = rev[j];
    float4 u = g4[(size_t)r * (HD / 4) + l];
    ax += u.x; ay += u.y; az += u.z; aw += u.w;
  }
  const float dc = dinv[c];
  float4 b = ((const float4*)bias)[l];
  float rx = ax * dc + b.x, ry = ay * dc + b.y, rz = az * dc + b.z, rw = aw * dc + b.w;
  if (do_relu) {
    rx = fmaxf(rx, 0.0f); ry = fmaxf(ry, 0.0f);
    rz = fmaxf(rz, 0.0f); rw = fmaxf(rw, 0.0f);
  }
  float4 o; o.x = rx; o.y = ry; o.z = rz; o.w = rw;
  ((float4*)out)[(size_t)c * (HD / 4) + l] = o;
}

// ===================== mean-pool + classifier =====================
__global__ __launch_bounds__(256) void colsum_kernel(const float* __restrict__ a, float* __restrict__ colsum)
{
  const int f = threadIdx.x;
  const int r0 = blockIdx.x * 64;
  float s = 0.0f;
  for (int r = 0; r < 64; ++r) s += a[(size_t)(r0 + r) * HD + f];
  atomicAdd(&colsum[f], s);
}

__global__ __launch_bounds__(256) void final_kernel(
    const float* __restrict__ colsum, const float* __restrict__ Wc,
    const float* __restrict__ bc, float* __restrict__ out)
{
  __shared__ float s0[256], s1[256];
  const int f = threadIdx.x;
  float bag = colsum[f] * (1.0f / (float)NN);
  s0[f] = bag * Wc[f * 2 + 0];
  s1[f] = bag * Wc[f * 2 + 1];
  __syncthreads();
  for (int st = 128; st; st >>= 1) {
    if (f < st) { s0[f] += s0[f + st]; s1[f] += s1[f + st]; }
    __syncthreads();
  }
  if (f == 0) { out[0] = s0[0] + bc[0]; out[1] = s1[0] + bc[1]; }
}

// ===================== launch =====================
extern "C" void kernel_launch(void* const* d_in, const int* in_sizes, int n_in,
                              void* d_out, int out_size, void* d_ws, size_t ws_size,
                              hipStream_t stream)
{
  const float* x   = (const float*)d_in[0];
  const float* Wp  = (const float*)d_in[1];
  const float* bp  = (const float*)d_in[2];
  const float* Wg1 = (const float*)d_in[3];
  const float* bg1 = (const float*)d_in[4];
  const float* Wg2 = (const float*)d_in[5];
  const float* bg2 = (const float*)d_in[6];
  const float* Wc  = (const float*)d_in[7];
  const float* bc  = (const float*)d_in[8];
  float* out = (float*)d_out;

  // workspace layout (~51.3 MB): 3 big NxHD buffers + graph arrays
  float* ws    = (float*)d_ws;
  float* h     = ws;                                // N*HD
  float* g     = ws + (size_t)NN * HD;              // N*HD
  float* h1    = ws + 2 * (size_t)NN * HD;          // N*HD
  float* agg2  = h;                                 // reuse (h dead after g2's GEMM input is h1)
  float* sq    = ws + 3 * (size_t)NN * HD;          // N
  float* dinv  = sq + NN;                           // N
  float* colsum= dinv + NN;                         // HD
  int* nbr = (int*)(colsum + HD);                   // N*KNN
  int* cnt = nbr + NN * KNN;                        // N
  int* off = cnt + NN;                              // N
  int* cur = off + NN;                              // N
  int* rev = cur + NN;                              // N*KNN

  // 1. h = relu(x @ W_proj + b_proj)
  gemm_4x8<true, true, false><<<dim3(NN / 64, HD / 128), dim3(256), 0, stream>>>(
      x, Wp, bp, nullptr, h, NN, HD, IND);
  // 2. sq[i] = ||h_i||^2
  sq_kernel<<<dim3(NN / 4), dim3(256), 0, stream>>>(h, sq);
  // 3. 5-NN per row
  dist_topk<<<dim3(NN / 64), dim3(256), 0, stream>>>(h, sq, nbr);
  // 4. in-degree counts
  hipMemsetAsync(cnt, 0, NN * sizeof(int), stream);
  count_kernel<<<dim3((NN * KNN) / 256), dim3(256), 0, stream>>>(nbr, cnt);
  // 5. dinv = 1/sqrt(deg)
  dinv_kernel<<<dim3(NN / 256), dim3(256), 0, stream>>>(cnt, dinv);
  // 6. CSR offsets
  scan_kernel<<<dim3(1), dim3(256), 0, stream>>>(cnt, off);
  // 7. reverse adjacency
  hipMemsetAsync(cur, 0, NN * sizeof(int), stream);
  fill_rev<<<dim3((NN * KNN) / 256), dim3(256), 0, stream>>>(nbr, off, cur, rev);
  // 8. g = (h @ W_g1) * dinv[row]
  gemm_4x8<false, false, true><<<dim3(NN / 64, HD / 128), dim3(256), 0, stream>>>(
      h, Wg1, nullptr, dinv, g, NN, HD, HD);
  // 9. h1 = relu(agg(g) + b_g1)
  aggregate<<<dim3(NN), dim3(64), 0, stream>>>(g, nbr, rev, off, cnt, dinv, bg1, h1, 1);
  // 10. g = (h1 @ W_g2) * dinv[row]
  gemm_4x8<false, false, true><<<dim3(NN / 64, HD / 128), dim3(256), 0, stream>>>(
      h1, Wg2, nullptr, dinv, g, NN, HD, HD);
  // 11. agg2 = agg(g) + b_g2   (no relu)
  aggregate<<<dim3(NN), dim3(64), 0, stream>>>(g, nbr, rev, off, cnt, dinv, bg2, agg2, 0);
  // 12/13. mean-pool + classifier head
  hipMemsetAsync(colsum, 0, HD * sizeof(float), stream);
  colsum_kernel<<<dim3(NN / 64), dim3(256), 0, stream>>>(agg2, colsum);
  final_kernel<<<dim3(1), dim3(256), 0, stream>>>(colsum, Wc, bc, out);
}

// Round 5
// 1813.846 us; speedup vs baseline: 2.4918x; 2.4918x over previous
//
#include <hip/hip_runtime.h>
#include <cstdint>
#include <cstddef>

#define NN 16384
#define IND 1024
#define HD 256
#define KNN 5
#define NCAND 16

typedef __attribute__((ext_vector_type(4))) float f32x4;
typedef __attribute__((ext_vector_type(8))) short bf16x8;

// ===================== GEMM: C = op(A@B [+bias][*rowscale[m]]) =====================
// 64x128 tile, 4x8 micro, 256 threads. A:MxK row-major, B:KxN row-major.
template<bool RELU, bool BIAS, bool RS>
__global__ __launch_bounds__(256) void gemm_4x8(
    const float* __restrict__ A, const float* __restrict__ B,
    const float* __restrict__ bias, const float* __restrict__ rowscale,
    float* __restrict__ C, int M, int Nc, int K)
{
  __shared__ float As[16][68];
  __shared__ float Bs[16][132];
  const int tid = threadIdx.x;
  const int tx = tid & 15, ty = tid >> 4;
  const int m0 = blockIdx.x * 64, n0 = blockIdx.y * 128;

  float acc[4][8];
  #pragma unroll
  for (int i = 0; i < 4; ++i)
    #pragma unroll
    for (int j = 0; j < 8; ++j) acc[i][j] = 0.0f;

  const int am  = tid >> 2;
  const int akq = (tid & 3) * 4;

  for (int kb = 0; kb < K; kb += 16) {
    {
      float4 v = *(const float4*)&A[(size_t)(m0 + am) * K + kb + akq];
      As[akq + 0][am] = v.x; As[akq + 1][am] = v.y;
      As[akq + 2][am] = v.z; As[akq + 3][am] = v.w;
    }
    #pragma unroll
    for (int c = 0; c < 2; ++c) {
      int idx = tid + c * 256;
      int k = idx >> 5;
      int f = idx & 31;
      float4 v = *(const float4*)&B[(size_t)(kb + k) * Nc + n0 + f * 4];
      *(float4*)&Bs[k][f * 4] = v;
    }
    __syncthreads();
    #pragma unroll
    for (int k = 0; k < 16; ++k) {
      float a[4], b[8];
      *(float4*)&a[0] = *(const float4*)&As[k][ty * 4];
      *(float4*)&b[0] = *(const float4*)&Bs[k][tx * 4];
      *(float4*)&b[4] = *(const float4*)&Bs[k][64 + tx * 4];
      #pragma unroll
      for (int i = 0; i < 4; ++i)
        #pragma unroll
        for (int j = 0; j < 8; ++j)
          acc[i][j] = fmaf(a[i], b[j], acc[i][j]);
    }
    __syncthreads();
  }

  float bvals[8];
  if (BIAS) {
    *(float4*)&bvals[0] = *(const float4*)&bias[n0 + tx * 4];
    *(float4*)&bvals[4] = *(const float4*)&bias[n0 + 64 + tx * 4];
  }
  #pragma unroll
  for (int i = 0; i < 4; ++i) {
    int m = m0 + ty * 4 + i;
    float rs = RS ? rowscale[m] : 1.0f;
    float o[8];
    #pragma unroll
    for (int j = 0; j < 8; ++j) {
      float v = acc[i][j];
      if (BIAS) v += bvals[j];
      if (RS) v *= rs;
      if (RELU) v = fmaxf(v, 0.0f);
      o[j] = v;
    }
    *(float4*)&C[(size_t)m * Nc + n0 + tx * 4]      = *(float4*)&o[0];
    *(float4*)&C[(size_t)m * Nc + n0 + 64 + tx * 4] = *(float4*)&o[4];
  }
}

// ===================== row squared norms =====================
__global__ __launch_bounds__(256) void sq_kernel(const float* __restrict__ h, float* __restrict__ sq)
{
  const int w = threadIdx.x >> 6, l = threadIdx.x & 63;
  const int r = blockIdx.x * 4 + w;
  float4 v = *(const float4*)&h[(size_t)r * HD + l * 4];
  float s = v.x * v.x + v.y * v.y + v.z * v.z + v.w * v.w;
  #pragma unroll
  for (int o = 32; o; o >>= 1) s += __shfl_down(s, o);
  if (l == 0) sq[r] = s;
}

// ===================== fp32 -> bf16 hi/lo split =====================
__device__ __forceinline__ ushort f2bf(float f) {
  uint32_t u = __float_as_uint(f);
  uint32_t r = (u + 0x7fffu + ((u >> 16) & 1u)) >> 16;
  return (ushort)r;
}
__device__ __forceinline__ float bf2f(ushort s) {
  return __uint_as_float(((uint32_t)s) << 16);
}

__global__ __launch_bounds__(256) void split_kernel(
    const float* __restrict__ h, ushort* __restrict__ hi, ushort* __restrict__ lo)
{
  int idx = blockIdx.x * 256 + threadIdx.x;   // one float4 per thread
  float4 v = ((const float4*)h)[idx];
  ushort a0 = f2bf(v.x), a1 = f2bf(v.y), a2 = f2bf(v.z), a3 = f2bf(v.w);
  ushort b0 = f2bf(v.x - bf2f(a0)), b1 = f2bf(v.y - bf2f(a1));
  ushort b2 = f2bf(v.z - bf2f(a2)), b3 = f2bf(v.w - bf2f(a3));
  ushort4 H; H.x = a0; H.y = a1; H.z = a2; H.w = a3;
  ushort4 L; L.x = b0; L.y = b1; L.z = b2; L.w = b3;
  ((ushort4*)hi)[idx] = H;
  ((ushort4*)lo)[idx] = L;
}

// top-5 insertion ladder (strict < : earlier-processed / lower index wins ties)
#define INS5(v, id, d, j) do {                                              \
    if ((d) < v[0]) {                                                       \
      v[4]=v[3]; id[4]=id[3]; v[3]=v[2]; id[3]=id[2];                       \
      v[2]=v[1]; id[2]=id[1]; v[1]=v[0]; id[1]=id[0];                       \
      v[0]=(d); id[0]=(j);                                                  \
    } else if ((d) < v[1]) {                                                \
      v[4]=v[3]; id[4]=id[3]; v[3]=v[2]; id[3]=id[2];                       \
      v[2]=v[1]; id[2]=id[1]; v[1]=(d); id[1]=(j);                          \
    } else if ((d) < v[2]) {                                                \
      v[4]=v[3]; id[4]=id[3]; v[3]=v[2]; id[3]=id[2]; v[2]=(d); id[2]=(j);  \
    } else if ((d) < v[3]) {                                                \
      v[4]=v[3]; id[4]=id[3]; v[3]=(d); id[3]=(j);                          \
    } else {                                                                \
      v[4]=(d); id[4]=(j);                                                  \
    }                                                                       \
  } while (0)

// ===================== MFMA pairwise-distance -> top-16 CANDIDATES =====================
// Gram via split-bf16 3-term: S = hi.hi + hi.lo + lo.hi.
// Block: 64 i-rows (panel LDS-resident), j streamed in 256-chunks, K=256.
// MFMA operands SWAPPED (A=j-frag, B=i-frag) so D rows=j, cols=i:
//   lane owns i = fi*16 + (lane&15); candidates j = (lane>>4)*4 + reg (+16*fj +64*wave).
// Per-lane top-5 per i-row in registers; 16-partial merge -> approx top-16 candidate
// list per row (exact fp32 rescore happens in a separate kernel).
__global__ __launch_bounds__(256) void dist_topk_mfma(
    const ushort* __restrict__ hhi, const ushort* __restrict__ hlo,
    const float* __restrict__ sq, int* __restrict__ cand)
{
  // LDS plan (bytes):
  //   iHi [64][264 us]  = 33792  @ 0       (row 528B)
  //   iLo [64][264 us]  = 33792  @ 33792
  //   jHi [256][40 us]  = 20480  @ 67584   (row 80B: 64B data + 16B pad)
  //   jLo [256][40 us]  = 20480  @ 88064
  //   sqs [256 f32]     = 1024   @ 108544
  //   merge M (alias @0): 64*176*4 = 45056
  __shared__ char smem[109568];
  ushort* iHi = (ushort*)(smem);
  ushort* iLo = (ushort*)(smem + 33792);
  ushort* jHi = (ushort*)(smem + 67584);
  ushort* jLo = (ushort*)(smem + 88064);
  float*  sqs = (float*)(smem + 108544);
  float*  M   = (float*)smem;

  const int tid  = threadIdx.x;
  const int wave = tid >> 6, lane = tid & 63;
  const int l15  = lane & 15, kgrp = lane >> 4;
  const int rbase = blockIdx.x * 64;

  // ---- stage i-panel (64 x 256, hi+lo), once ----
  // 4 threads/row, 64 ushorts (= 8 x uint4) each.  [FIX: was 4 x uint4 = half]
  {
    const int r = tid >> 2, q = tid & 3;
    const uint4* sH = (const uint4*)&hhi[(size_t)(rbase + r) * HD + q * 64];
    const uint4* sL = (const uint4*)&hlo[(size_t)(rbase + r) * HD + q * 64];
    uint4* dH = (uint4*)&iHi[r * 264 + q * 64];
    uint4* dL = (uint4*)&iLo[r * 264 + q * 64];
    #pragma unroll
    for (int c = 0; c < 8; ++c) { dH[c] = sH[c]; dL[c] = sL[c]; }
  }

  float bv[4][5]; int bi[4][5];
  #pragma unroll
  for (int i = 0; i < 4; ++i)
    #pragma unroll
    for (int s = 0; s < 5; ++s) { bv[i][s] = 3.0e38f; bi[i][s] = 0; }

  for (int j0 = 0; j0 < NN; j0 += 256) {
    f32x4 acc[4][4];
    #pragma unroll
    for (int fi = 0; fi < 4; ++fi)
      #pragma unroll
      for (int fj = 0; fj < 4; ++fj) acc[fi][fj] = (f32x4){0.f, 0.f, 0.f, 0.f};

    #pragma unroll 1
    for (int kb = 0; kb < 8; ++kb) {
      // issue global loads for this 32-k slice of the j-chunk (before barrier).
      // 32 ushorts = 4 x uint4 per row.  [FIX: was 2 x uint4 = half]
      const uint4* sH = (const uint4*)&hhi[(size_t)(j0 + tid) * HD + kb * 32];
      const uint4* sL = (const uint4*)&hlo[(size_t)(j0 + tid) * HD + kb * 32];
      uint4 gh0 = sH[0], gh1 = sH[1], gh2 = sH[2], gh3 = sH[3];
      uint4 gl0 = sL[0], gl1 = sL[1], gl2 = sL[2], gl3 = sL[3];
      float sqv_stage = (kb == 0) ? sq[j0 + tid] : 0.0f;
      __syncthreads();   // previous iteration's reads of jHi/jLo (and sqs) complete
      {
        uint4* dH = (uint4*)&jHi[tid * 40];
        uint4* dL = (uint4*)&jLo[tid * 40];
        dH[0] = gh0; dH[1] = gh1; dH[2] = gh2; dH[3] = gh3;
        dL[0] = gl0; dL[1] = gl1; dL[2] = gl2; dL[3] = gl3;
        if (kb == 0) sqs[tid] = sqv_stage;
      }
      __syncthreads();

      // i-fragments (MFMA B operand): 8 x ds_read_b128
      bf16x8 bH[4], bL[4];
      #pragma unroll
      for (int f = 0; f < 4; ++f) {
        const int ir = f * 16 + l15;
        bH[f] = *(const bf16x8*)&iHi[ir * 264 + kb * 32 + kgrp * 8];
        bL[f] = *(const bf16x8*)&iLo[ir * 264 + kb * 32 + kgrp * 8];
      }
      // j-fragments (MFMA A operand) + 48 MFMA
      #pragma unroll
      for (int fj = 0; fj < 4; ++fj) {
        const int jr = wave * 64 + fj * 16 + l15;
        bf16x8 aH = *(const bf16x8*)&jHi[jr * 40 + kgrp * 8];
        bf16x8 aL = *(const bf16x8*)&jLo[jr * 40 + kgrp * 8];
        #pragma unroll
        for (int fi = 0; fi < 4; ++fi) {
          acc[fi][fj] = __builtin_amdgcn_mfma_f32_16x16x32_bf16(aH, bH[fi], acc[fi][fj], 0, 0, 0);
          acc[fi][fj] = __builtin_amdgcn_mfma_f32_16x16x32_bf16(aH, bL[fi], acc[fi][fj], 0, 0, 0);
          acc[fi][fj] = __builtin_amdgcn_mfma_f32_16x16x32_bf16(aL, bH[fi], acc[fi][fj], 0, 0, 0);
        }
      }
    }

    // epilogue: d = sq[j] - 2*S, insert into per-lane top-5 ladders
    float sqv[16];
    #pragma unroll
    for (int fj = 0; fj < 4; ++fj)
      #pragma unroll
      for (int r = 0; r < 4; ++r)
        sqv[fj * 4 + r] = sqs[wave * 64 + fj * 16 + kgrp * 4 + r];

    #pragma unroll
    for (int fi = 0; fi < 4; ++fi) {
      const int ig = rbase + fi * 16 + l15;
      #pragma unroll
      for (int fj = 0; fj < 4; ++fj) {
        #pragma unroll
        for (int r = 0; r < 4; ++r) {
          const int jg = j0 + wave * 64 + fj * 16 + kgrp * 4 + r;
          float d = fmaf(-2.0f, acc[fi][fj][r], sqv[fj * 4 + r]);
          if (jg != ig && d < bv[fi][4]) {
            INS5(bv[fi], bi[fi], d, jg);
          }
        }
      }
    }
  }

  // ---- merge 16 partial top-5s per row -> approx top-16 candidates ----
  __syncthreads();
  const int part = wave * 4 + kgrp;
  #pragma unroll
  for (int fi = 0; fi < 4; ++fi) {
    const int row = fi * 16 + l15;
    #pragma unroll
    for (int s = 0; s < 5; ++s) {
      M[row * 176 + part * 5 + s]      = bv[fi][s];
      M[row * 176 + 88 + part * 5 + s] = __int_as_float(bi[fi][s]);
    }
  }
  __syncthreads();
  if (tid < 64) {
    const int irow = rbase + tid;
    #pragma unroll 1
    for (int s = 0; s < NCAND; ++s) {
      float bestv = 3.0e38f; int bestid = 0x7fffffff; int bestt = 0;
      #pragma unroll 1
      for (int t = 0; t < 80; ++t) {
        float v = M[tid * 176 + t];
        int id = __float_as_int(M[tid * 176 + 88 + t]);
        if (v < bestv || (v == bestv && id < bestid)) { bestv = v; bestid = id; bestt = t; }
      }
      M[tid * 176 + bestt] = 3.0e38f;
      cand[irow * NCAND + s] = bestid;
    }
  }
}

// ===================== exact fp32 rescore of candidates -> top-5 =====================
// One wave per row. 4 lanes per candidate, 64 dims each. Ranking form identical to
// the round-2 fp32 kernel (d = sq[j] - 2*dot, tie -> lower index), which matched JAX.
__global__ __launch_bounds__(64) void rescore_kernel(
    const float* __restrict__ h, const float* __restrict__ sq,
    const int* __restrict__ cand, int* __restrict__ nbr)
{
  __shared__ float hi_s[HD];
  __shared__ float dv[NCAND];
  __shared__ int   di[NCAND];
  const int i = blockIdx.x;
  const int lane = threadIdx.x;          // 64 threads = 1 wave
  *(float4*)&hi_s[lane * 4] = *(const float4*)&h[(size_t)i * HD + lane * 4];
  __syncthreads();
  const int c = lane >> 2, q = lane & 3; // candidate c, quarter q
  const int j = cand[i * NCAND + c];
  float s = 0.f;
  const float4* hj  = (const float4*)&h[(size_t)j * HD + q * 64];
  const float4* hi4 = (const float4*)&hi_s[q * 64];
  #pragma unroll
  for (int t = 0; t < 16; ++t) {
    float4 a = hi4[t], b = hj[t];
    s = fmaf(a.x, b.x, s); s = fmaf(a.y, b.y, s);
    s = fmaf(a.z, b.z, s); s = fmaf(a.w, b.w, s);
  }
  s += __shfl_down(s, 1);
  s += __shfl_down(s, 2);
  if (q == 0) { dv[c] = fmaf(-2.0f, s, sq[j]); di[c] = j; }
  __syncthreads();
  if (lane == 0) {
    #pragma unroll 1
    for (int sidx = 0; sidx < KNN; ++sidx) {
      float bestv = 3.0e38f; int bestid = 0x7fffffff; int bestc = 0;
      #pragma unroll 1
      for (int t = 0; t < NCAND; ++t) {
        float v = dv[t]; int id = di[t];
        if (v < bestv || (v == bestv && id < bestid)) { bestv = v; bestid = id; bestc = t; }
      }
      dv[bestc] = 3.0e38f;
      nbr[i * KNN + sidx] = bestid;
    }
  }
}

// ===================== graph build =====================
__global__ void count_kernel(const int* __restrict__ nbr, int* __restrict__ cnt)
{
  int e = blockIdx.x * 256 + threadIdx.x;
  if (e < NN * KNN) atomicAdd(&cnt[nbr[e]], 1);
}

__global__ void dinv_kernel(const int* __restrict__ cnt, float* __restrict__ dinv)
{
  int i = blockIdx.x * 256 + threadIdx.x;
  if (i < NN) dinv[i] = 1.0f / sqrtf((float)(cnt[i] + KNN + 1));  // deg = indeg + K + 1
}

__global__ __launch_bounds__(256) void scan_kernel(const int* __restrict__ cnt, int* __restrict__ off)
{
  __shared__ int ps[256];
  const int t = threadIdx.x;
  int s = 0;
  for (int i = 0; i < 64; ++i) s += cnt[t * 64 + i];
  ps[t] = s;
  __syncthreads();
  if (t == 0) {
    int run = 0;
    for (int q = 0; q < 256; ++q) { int v = ps[q]; ps[q] = run; run += v; }
  }
  __syncthreads();
  int base = ps[t];
  for (int i = 0; i < 64; ++i) { off[t * 64 + i] = base; base += cnt[t * 64 + i]; }
}

__global__ void fill_rev(const int* __restrict__ nbr, const int* __restrict__ off,
                         int* __restrict__ cur, int* __restrict__ rev)
{
  int e = blockIdx.x * 256 + threadIdx.x;
  if (e < NN * KNN) {
    int i = e / KNN;
    int c = nbr[e];
    int s = atomicAdd(&cur[c], 1);
    rev[off[c] + s] = i;
  }
}

// ===================== GCN aggregation (pure gather via reverse CSR) =====================
__global__ __launch_bounds__(64) void aggregate(
    const float* __restrict__ g, const int* __restrict__ nbr,
    const int* __restrict__ rev, const int* __restrict__ off, const int* __restrict__ cnt,
    const float* __restrict__ dinv, const float* __restrict__ bias,
    float* __restrict__ out, int do_relu)
{
  const int c = blockIdx.x;
  const int l = threadIdx.x;
  const float4* g4 = (const float4*)g;
  float4 v = g4[(size_t)c * (HD / 4) + l];
  float ax = v.x, ay = v.y, az = v.z, aw = v.w;
  #pragma unroll
  for (int k = 0; k < KNN; ++k) {
    int r = nbr[c * KNN + k];
    float4 u = g4[(size_t)r * (HD / 4) + l];
    ax += u.x; ay += u.y; az += u.z; aw += u.w;
  }
  const int o0 = off[c], o1 = o0 + cnt[c];
  for (int j = o0; j < o1; ++j) {
    int r = rev[j];
    float4 u = g4[(size_t)r * (HD / 4) + l];
    ax += u.x; ay += u.y; az += u.z; aw += u.w;
  }
  const float dc = dinv[c];
  float4 b = ((const float4*)bias)[l];
  float rx = ax * dc + b.x, ry = ay * dc + b.y, rz = az * dc + b.z, rw = aw * dc + b.w;
  if (do_relu) {
    rx = fmaxf(rx, 0.0f); ry = fmaxf(ry, 0.0f);
    rz = fmaxf(rz, 0.0f); rw = fmaxf(rw, 0.0f);
  }
  float4 o; o.x = rx; o.y = ry; o.z = rz; o.w = rw;
  ((float4*)out)[(size_t)c * (HD / 4) + l] = o;
}

// ===================== mean-pool + classifier =====================
__global__ __launch_bounds__(256) void colsum_kernel(const float* __restrict__ a, float* __restrict__ colsum)
{
  const int f = threadIdx.x;
  const int r0 = blockIdx.x * 64;
  float s = 0.0f;
  for (int r = 0; r < 64; ++r) s += a[(size_t)(r0 + r) * HD + f];
  atomicAdd(&colsum[f], s);
}

__global__ __launch_bounds__(256) void final_kernel(
    const float* __restrict__ colsum, const float* __restrict__ Wc,
    const float* __restrict__ bc, float* __restrict__ out)
{
  __shared__ float s0[256], s1[256];
  const int f = threadIdx.x;
  float bag = colsum[f] * (1.0f / (float)NN);
  s0[f] = bag * Wc[f * 2 + 0];
  s1[f] = bag * Wc[f * 2 + 1];
  __syncthreads();
  for (int st = 128; st; st >>= 1) {
    if (f < st) { s0[f] += s0[f + st]; s1[f] += s1[f + st]; }
    __syncthreads();
  }
  if (f == 0) { out[0] = s0[0] + bc[0]; out[1] = s1[0] + bc[1]; }
}

// ===================== launch =====================
extern "C" void kernel_launch(void* const* d_in, const int* in_sizes, int n_in,
                              void* d_out, int out_size, void* d_ws, size_t ws_size,
                              hipStream_t stream)
{
  const float* x   = (const float*)d_in[0];
  const float* Wp  = (const float*)d_in[1];
  const float* bp  = (const float*)d_in[2];
  const float* Wg1 = (const float*)d_in[3];
  const float* bg1 = (const float*)d_in[4];
  const float* Wg2 = (const float*)d_in[5];
  const float* bg2 = (const float*)d_in[6];
  const float* Wc  = (const float*)d_in[7];
  const float* bc  = (const float*)d_in[8];
  float* out = (float*)d_out;

  float* ws    = (float*)d_ws;
  float* h     = ws;                                // N*HD f32
  float* g     = ws + (size_t)NN * HD;              // N*HD f32 (written step 8)
  float* h1    = ws + 2 * (size_t)NN * HD;          // N*HD f32 (written step 9)
  float* agg2  = h;                                 // reuse
  float* sq    = ws + 3 * (size_t)NN * HD;          // N
  float* dinv  = sq + NN;                           // N
  float* colsum= dinv + NN;                         // HD
  int* nbr = (int*)(colsum + HD);                   // N*KNN
  int* cnt = nbr + NN * KNN;                        // N
  int* off = cnt + NN;                              // N
  int* cur = off + NN;                              // N
  int* rev = cur + NN;                              // N*KNN
  // bf16 hi/lo live in g / h1 regions (dead until steps 8/9, after kNN phase)
  ushort* hhi = (ushort*)g;                         // first 8 MB of g region
  ushort* hlo = (ushort*)h1;
  // candidate list lives in upper quarter of g region (byte offset 12 MB; hhi ends at 8 MB)
  int* cand = (int*)(g + (size_t)NN * HD * 3 / 4);  // N*NCAND ints = 1 MB

  // 1. h = relu(x @ W_proj + b_proj)
  gemm_4x8<true, true, false><<<dim3(NN / 64, HD / 128), dim3(256), 0, stream>>>(
      x, Wp, bp, nullptr, h, NN, HD, IND);
  // 2. sq[i] = ||h_i||^2 ; split h into bf16 hi/lo
  sq_kernel<<<dim3(NN / 4), dim3(256), 0, stream>>>(h, sq);
  split_kernel<<<dim3(NN * HD / 4 / 256), dim3(256), 0, stream>>>(h, hhi, hlo);
  // 3a. approx top-16 candidates per row (MFMA Gram)
  dist_topk_mfma<<<dim3(NN / 64), dim3(256), 0, stream>>>(hhi, hlo, sq, cand);
  // 3b. exact fp32 rescore -> top-5
  rescore_kernel<<<dim3(NN), dim3(64), 0, stream>>>(h, sq, cand, nbr);
  // 4. in-degree counts
  hipMemsetAsync(cnt, 0, NN * sizeof(int), stream);
  count_kernel<<<dim3((NN * KNN) / 256), dim3(256), 0, stream>>>(nbr, cnt);
  // 5. dinv
  dinv_kernel<<<dim3(NN / 256), dim3(256), 0, stream>>>(cnt, dinv);
  // 6. CSR offsets
  scan_kernel<<<dim3(1), dim3(256), 0, stream>>>(cnt, off);
  // 7. reverse adjacency
  hipMemsetAsync(cur, 0, NN * sizeof(int), stream);
  fill_rev<<<dim3((NN * KNN) / 256), dim3(256), 0, stream>>>(nbr, off, cur, rev);
  // 8. g = (h @ W_g1) * dinv[row]
  gemm_4x8<false, false, true><<<dim3(NN / 64, HD / 128), dim3(256), 0, stream>>>(
      h, Wg1, nullptr, dinv, g, NN, HD, HD);
  // 9. h1 = relu(agg(g) + b_g1)
  aggregate<<<dim3(NN), dim3(64), 0, stream>>>(g, nbr, rev, off, cnt, dinv, bg1, h1, 1);
  // 10. g = (h1 @ W_g2) * dinv[row]
  gemm_4x8<false, false, true><<<dim3(NN / 64, HD / 128), dim3(256), 0, stream>>>(
      h1, Wg2, nullptr, dinv, g, NN, HD, HD);
  // 11. agg2 = agg(g) + b_g2
  aggregate<<<dim3(NN), dim3(64), 0, stream>>>(g, nbr, rev, off, cnt, dinv, bg2, agg2, 0);
  // 12/13. mean-pool + classifier
  hipMemsetAsync(colsum, 0, HD * sizeof(float), stream);
  colsum_kernel<<<dim3(NN / 64), dim3(256), 0, stream>>>(agg2, colsum);
  final_kernel<<<dim3(1), dim3(256), 0, stream>>>(colsum, Wc, bc, out);
}

// Round 6
// 1168.237 us; speedup vs baseline: 3.8689x; 1.5526x over previous
//
#include <hip/hip_runtime.h>
#include <cstdint>
#include <cstddef>

#define NN 16384
#define IND 1024
#define HD 256
#define KNN 5
#define NCAND 16   // per j-half
#define NC2 32     // total candidates per row (2 halves)

typedef __attribute__((ext_vector_type(4))) float f32x4;
typedef __attribute__((ext_vector_type(8))) short bf16x8;

// ===================== GEMM: C = op(A@B [+bias][*rowscale[m]]) =====================
// 64x128 tile, 4x8 micro, 256 threads. A:MxK row-major, B:KxN row-major.
template<bool RELU, bool BIAS, bool RS>
__global__ __launch_bounds__(256) void gemm_4x8(
    const float* __restrict__ A, const float* __restrict__ B,
    const float* __restrict__ bias, const float* __restrict__ rowscale,
    float* __restrict__ C, int M, int Nc, int K)
{
  __shared__ float As[16][68];
  __shared__ float Bs[16][132];
  const int tid = threadIdx.x;
  const int tx = tid & 15, ty = tid >> 4;
  const int m0 = blockIdx.x * 64, n0 = blockIdx.y * 128;

  float acc[4][8];
  #pragma unroll
  for (int i = 0; i < 4; ++i)
    #pragma unroll
    for (int j = 0; j < 8; ++j) acc[i][j] = 0.0f;

  const int am  = tid >> 2;
  const int akq = (tid & 3) * 4;

  for (int kb = 0; kb < K; kb += 16) {
    {
      float4 v = *(const float4*)&A[(size_t)(m0 + am) * K + kb + akq];
      As[akq + 0][am] = v.x; As[akq + 1][am] = v.y;
      As[akq + 2][am] = v.z; As[akq + 3][am] = v.w;
    }
    #pragma unroll
    for (int c = 0; c < 2; ++c) {
      int idx = tid + c * 256;
      int k = idx >> 5;
      int f = idx & 31;
      float4 v = *(const float4*)&B[(size_t)(kb + k) * Nc + n0 + f * 4];
      *(float4*)&Bs[k][f * 4] = v;
    }
    __syncthreads();
    #pragma unroll
    for (int k = 0; k < 16; ++k) {
      float a[4], b[8];
      *(float4*)&a[0] = *(const float4*)&As[k][ty * 4];
      *(float4*)&b[0] = *(const float4*)&Bs[k][tx * 4];
      *(float4*)&b[4] = *(const float4*)&Bs[k][64 + tx * 4];
      #pragma unroll
      for (int i = 0; i < 4; ++i)
        #pragma unroll
        for (int j = 0; j < 8; ++j)
          acc[i][j] = fmaf(a[i], b[j], acc[i][j]);
    }
    __syncthreads();
  }

  float bvals[8];
  if (BIAS) {
    *(float4*)&bvals[0] = *(const float4*)&bias[n0 + tx * 4];
    *(float4*)&bvals[4] = *(const float4*)&bias[n0 + 64 + tx * 4];
  }
  #pragma unroll
  for (int i = 0; i < 4; ++i) {
    int m = m0 + ty * 4 + i;
    float rs = RS ? rowscale[m] : 1.0f;
    float o[8];
    #pragma unroll
    for (int j = 0; j < 8; ++j) {
      float v = acc[i][j];
      if (BIAS) v += bvals[j];
      if (RS) v *= rs;
      if (RELU) v = fmaxf(v, 0.0f);
      o[j] = v;
    }
    *(float4*)&C[(size_t)m * Nc + n0 + tx * 4]      = *(float4*)&o[0];
    *(float4*)&C[(size_t)m * Nc + n0 + 64 + tx * 4] = *(float4*)&o[4];
  }
}

// ===================== row squared norms =====================
__global__ __launch_bounds__(256) void sq_kernel(const float* __restrict__ h, float* __restrict__ sq)
{
  const int w = threadIdx.x >> 6, l = threadIdx.x & 63;
  const int r = blockIdx.x * 4 + w;
  float4 v = *(const float4*)&h[(size_t)r * HD + l * 4];
  float s = v.x * v.x + v.y * v.y + v.z * v.z + v.w * v.w;
  #pragma unroll
  for (int o = 32; o; o >>= 1) s += __shfl_down(s, o);
  if (l == 0) sq[r] = s;
}

// ===================== fp32 -> bf16 hi/lo split =====================
__device__ __forceinline__ ushort f2bf(float f) {
  uint32_t u = __float_as_uint(f);
  uint32_t r = (u + 0x7fffu + ((u >> 16) & 1u)) >> 16;
  return (ushort)r;
}
__device__ __forceinline__ float bf2f(ushort s) {
  return __uint_as_float(((uint32_t)s) << 16);
}

__global__ __launch_bounds__(256) void split_kernel(
    const float* __restrict__ h, ushort* __restrict__ hi, ushort* __restrict__ lo)
{
  int idx = blockIdx.x * 256 + threadIdx.x;   // one float4 per thread
  float4 v = ((const float4*)h)[idx];
  ushort a0 = f2bf(v.x), a1 = f2bf(v.y), a2 = f2bf(v.z), a3 = f2bf(v.w);
  ushort b0 = f2bf(v.x - bf2f(a0)), b1 = f2bf(v.y - bf2f(a1));
  ushort b2 = f2bf(v.z - bf2f(a2)), b3 = f2bf(v.w - bf2f(a3));
  ushort4 H; H.x = a0; H.y = a1; H.z = a2; H.w = a3;
  ushort4 L; L.x = b0; L.y = b1; L.z = b2; L.w = b3;
  ((ushort4*)hi)[idx] = H;
  ((ushort4*)lo)[idx] = L;
}

// top-5 insertion ladder (strict < so earlier-inserted wins ties)
#define INS5(v, id, d, j) do {                                              \
    if ((d) < v[0]) {                                                       \
      v[4]=v[3]; id[4]=id[3]; v[3]=v[2]; id[3]=id[2];                       \
      v[2]=v[1]; id[2]=id[1]; v[1]=v[0]; id[1]=id[0];                       \
      v[0]=(d); id[0]=(j);                                                  \
    } else if ((d) < v[1]) {                                                \
      v[4]=v[3]; id[4]=id[3]; v[3]=v[2]; id[3]=id[2];                       \
      v[2]=v[1]; id[2]=id[1]; v[1]=(d); id[1]=(j);                          \
    } else if ((d) < v[2]) {                                                \
      v[4]=v[3]; id[4]=id[3]; v[3]=v[2]; id[3]=id[2]; v[2]=(d); id[2]=(j);  \
    } else if ((d) < v[3]) {                                                \
      v[4]=v[3]; id[4]=id[3]; v[3]=(d); id[3]=(j);                          \
    } else {                                                                \
      v[4]=(d); id[4]=(j);                                                  \
    }                                                                       \
  } while (0)

// ===================== MFMA pairwise-distance -> top-16 candidates per j-half ==========
// Gram via split-bf16 3-term: S = hi.hi + hi.lo + lo.hi.
// Block: 128 i-rows (LDS-resident panel, 132KB), 512 threads (8 waves), j-HALF streamed
// in 256-chunks with A-operand (j-fragments) loaded DIRECTLY from global (L2/L3-hot) —
// no j staging, no barriers in the K-loop. grid = (128 row-panels, 2 j-halves).
// MFMA operands swapped (A=j, B=i): lane owns i = fi*16+(lane&15);
// j = wave*32 + fj*16 + (lane>>4)*4 + reg.
// Per-lane top-5 ladders -> kgrp shuffle-merge -> per-wave top-5 -> LDS merge -> top-16.
__global__ __launch_bounds__(512, 2) void dist_topk_mfma(
    const ushort* __restrict__ hhi, const ushort* __restrict__ hlo,
    const float* __restrict__ sq, int* __restrict__ cand)
{
  // iHi [128][264 us] = 67584 B @ 0 ; iLo same @ 67584.  Total 135168 B.
  // merge M aliases @0: 128 rows x 80 floats = 40960 B.
  __shared__ char smem[135168];
  ushort* iHi = (ushort*)smem;
  ushort* iLo = (ushort*)(smem + 67584);
  float*  M   = (float*)smem;

  const int tid  = threadIdx.x;
  const int wave = tid >> 6, lane = tid & 63;
  const int l15  = lane & 15, kgrp = lane >> 4;
  const int rbase = blockIdx.x * 128;
  const int jbeg  = blockIdx.y * (NN / 2);

  // ---- stage i-panel (128 x 256, hi+lo), once: 4 threads/row, 64 us (8 x uint4) each
  {
    const int r = tid >> 2, q = tid & 3;
    const uint4* sH = (const uint4*)&hhi[(size_t)(rbase + r) * HD + q * 64];
    const uint4* sL = (const uint4*)&hlo[(size_t)(rbase + r) * HD + q * 64];
    uint4* dH = (uint4*)&iHi[r * 264 + q * 64];
    uint4* dL = (uint4*)&iLo[r * 264 + q * 64];
    #pragma unroll
    for (int c = 0; c < 8; ++c) { dH[c] = sH[c]; dL[c] = sL[c]; }
  }
  __syncthreads();

  float bv[8][5]; int bi[8][5];
  #pragma unroll
  for (int i = 0; i < 8; ++i)
    #pragma unroll
    for (int s = 0; s < 5; ++s) { bv[i][s] = 3.0e38f; bi[i][s] = 0; }

  for (int j0 = jbeg; j0 < jbeg + NN / 2; j0 += 256) {
    f32x4 acc[8][2];
    #pragma unroll
    for (int fi = 0; fi < 8; ++fi)
      #pragma unroll
      for (int fj = 0; fj < 2; ++fj) acc[fi][fj] = (f32x4){0.f, 0.f, 0.f, 0.f};

    #pragma unroll 2
    for (int kb = 0; kb < 8; ++kb) {
      // A-fragments (j side) straight from global — L2/L3-cached stream
      bf16x8 aH[2], aL[2];
      #pragma unroll
      for (int fj = 0; fj < 2; ++fj) {
        const size_t jr = (size_t)(j0 + wave * 32 + fj * 16 + l15);
        aH[fj] = *(const bf16x8*)&hhi[jr * HD + kb * 32 + kgrp * 8];
        aL[fj] = *(const bf16x8*)&hlo[jr * HD + kb * 32 + kgrp * 8];
      }
      // B-fragments (i side) from LDS + 48 MFMA
      #pragma unroll
      for (int fi = 0; fi < 8; ++fi) {
        const int ir = fi * 16 + l15;
        bf16x8 bH = *(const bf16x8*)&iHi[ir * 264 + kb * 32 + kgrp * 8];
        bf16x8 bL = *(const bf16x8*)&iLo[ir * 264 + kb * 32 + kgrp * 8];
        #pragma unroll
        for (int fj = 0; fj < 2; ++fj) {
          acc[fi][fj] = __builtin_amdgcn_mfma_f32_16x16x32_bf16(aH[fj], bH, acc[fi][fj], 0, 0, 0);
          acc[fi][fj] = __builtin_amdgcn_mfma_f32_16x16x32_bf16(aH[fj], bL, acc[fi][fj], 0, 0, 0);
          acc[fi][fj] = __builtin_amdgcn_mfma_f32_16x16x32_bf16(aL[fj], bH, acc[fi][fj], 0, 0, 0);
        }
      }
    }

    // epilogue: d = sq[j] - 2*S -> per-lane ladders
    float4 sqa = *(const float4*)&sq[j0 + wave * 32 + kgrp * 4];
    float4 sqb = *(const float4*)&sq[j0 + wave * 32 + 16 + kgrp * 4];
    float sqv[2][4] = { { sqa.x, sqa.y, sqa.z, sqa.w }, { sqb.x, sqb.y, sqb.z, sqb.w } };

    #pragma unroll
    for (int fi = 0; fi < 8; ++fi) {
      const int ig = rbase + fi * 16 + l15;
      #pragma unroll
      for (int fj = 0; fj < 2; ++fj) {
        #pragma unroll
        for (int r = 0; r < 4; ++r) {
          const int jg = j0 + wave * 32 + fj * 16 + kgrp * 4 + r;
          float d = fmaf(-2.0f, acc[fi][fj][r], sqv[fj][r]);
          if (jg != ig && d < bv[fi][4]) {
            INS5(bv[fi], bi[fi], d, jg);
          }
        }
      }
    }
  }

  // ---- merge the 4 kgrp partials within each wave (shuffle butterfly over lane bits 4,5)
  #pragma unroll
  for (int fi = 0; fi < 8; ++fi) {
    #pragma unroll
    for (int m = 16; m <= 32; m <<= 1) {
      float ov[5]; int oi[5];
      #pragma unroll
      for (int s = 0; s < 5; ++s) {
        ov[s] = __shfl_xor(bv[fi][s], m);
        oi[s] = __shfl_xor(bi[fi][s], m);
      }
      #pragma unroll
      for (int s = 0; s < 5; ++s) {
        if (ov[s] < bv[fi][4]) { INS5(bv[fi], bi[fi], ov[s], oi[s]); }
      }
    }
  }

  // ---- 8 wave-partials x 5 per row -> LDS -> top-16 candidates for this j-half
  __syncthreads();   // i-panel reads complete; reuse LDS as M
  if (kgrp == 0) {
    #pragma unroll
    for (int fi = 0; fi < 8; ++fi) {
      const int row = fi * 16 + l15;
      #pragma unroll
      for (int s = 0; s < 5; ++s) {
        M[row * 80 + wave * 5 + s]      = bv[fi][s];
        M[row * 80 + 40 + wave * 5 + s] = __int_as_float(bi[fi][s]);
      }
    }
  }
  __syncthreads();
  if (tid < 128) {
    const int irow = rbase + tid;
    int* co = &cand[(size_t)irow * NC2 + blockIdx.y * NCAND];
    #pragma unroll 1
    for (int s = 0; s < NCAND; ++s) {
      float bestv = 3.0e38f; int bestid = 0x7fffffff; int bestt = 0;
      #pragma unroll 1
      for (int t = 0; t < 40; ++t) {
        float v = M[tid * 80 + t];
        int id = __float_as_int(M[tid * 80 + 40 + t]);
        if (v < bestv || (v == bestv && id < bestid)) { bestv = v; bestid = id; bestt = t; }
      }
      M[tid * 80 + bestt] = 3.0e38f;
      co[s] = bestid;
    }
  }
}

// ===================== exact fp32 rescore of 32 candidates -> top-5 =====================
// 128 threads (2 waves) per row: 4 lanes per candidate, 64 dims each. Ranking identical
// to the round-2 exact fp32 kernel (d = sq[j] - 2*dot, tie -> lower index).
__global__ __launch_bounds__(128) void rescore_kernel(
    const float* __restrict__ h, const float* __restrict__ sq,
    const int* __restrict__ cand, int* __restrict__ nbr)
{
  __shared__ float hi_s[HD];
  __shared__ float dv[NC2];
  __shared__ int   di[NC2];
  const int i = blockIdx.x;
  const int t = threadIdx.x;             // 0..127
  if (t < 64) *(float4*)&hi_s[t * 4] = *(const float4*)&h[(size_t)i * HD + t * 4];
  __syncthreads();
  const int c = t >> 2, q = t & 3;       // candidate c (0..31), quarter q
  const int j = cand[(size_t)i * NC2 + c];
  float s = 0.f;
  const float4* hj  = (const float4*)&h[(size_t)j * HD + q * 64];
  const float4* hi4 = (const float4*)&hi_s[q * 64];
  #pragma unroll
  for (int u = 0; u < 16; ++u) {
    float4 a = hi4[u], b = hj[u];
    s = fmaf(a.x, b.x, s); s = fmaf(a.y, b.y, s);
    s = fmaf(a.z, b.z, s); s = fmaf(a.w, b.w, s);
  }
  s += __shfl_down(s, 1);
  s += __shfl_down(s, 2);
  if (q == 0) { dv[c] = fmaf(-2.0f, s, sq[j]); di[c] = j; }
  __syncthreads();
  if (t == 0) {
    #pragma unroll 1
    for (int sidx = 0; sidx < KNN; ++sidx) {
      float bestv = 3.0e38f; int bestid = 0x7fffffff; int bestc = 0;
      #pragma unroll 1
      for (int u = 0; u < NC2; ++u) {
        float v = dv[u]; int id = di[u];
        if (v < bestv || (v == bestv && id < bestid)) { bestv = v; bestid = id; bestc = u; }
      }
      dv[bestc] = 3.0e38f;
      nbr[i * KNN + sidx] = bestid;
    }
  }
}

// ===================== graph build =====================
__global__ void count_kernel(const int* __restrict__ nbr, int* __restrict__ cnt)
{
  int e = blockIdx.x * 256 + threadIdx.x;
  if (e < NN * KNN) atomicAdd(&cnt[nbr[e]], 1);
}

__global__ void dinv_kernel(const int* __restrict__ cnt, float* __restrict__ dinv)
{
  int i = blockIdx.x * 256 + threadIdx.x;
  if (i < NN) dinv[i] = 1.0f / sqrtf((float)(cnt[i] + KNN + 1));  // deg = indeg + K + 1
}

__global__ __launch_bounds__(256) void scan_kernel(const int* __restrict__ cnt, int* __restrict__ off)
{
  __shared__ int ps[256];
  const int t = threadIdx.x;
  int s = 0;
  for (int i = 0; i < 64; ++i) s += cnt[t * 64 + i];
  ps[t] = s;
  __syncthreads();
  if (t == 0) {
    int run = 0;
    for (int q = 0; q < 256; ++q) { int v = ps[q]; ps[q] = run; run += v; }
  }
  __syncthreads();
  int base = ps[t];
  for (int i = 0; i < 64; ++i) { off[t * 64 + i] = base; base += cnt[t * 64 + i]; }
}

__global__ void fill_rev(const int* __restrict__ nbr, const int* __restrict__ off,
                         int* __restrict__ cur, int* __restrict__ rev)
{
  int e = blockIdx.x * 256 + threadIdx.x;
  if (e < NN * KNN) {
    int i = e / KNN;
    int c = nbr[e];
    int s = atomicAdd(&cur[c], 1);
    rev[off[c] + s] = i;
  }
}

// ===================== GCN aggregation (pure gather via reverse CSR) =====================
__global__ __launch_bounds__(64) void aggregate(
    const float* __restrict__ g, const int* __restrict__ nbr,
    const int* __restrict__ rev, const int* __restrict__ off, const int* __restrict__ cnt,
    const float* __restrict__ dinv, const float* __restrict__ bias,
    float* __restrict__ out, int do_relu)
{
  const int c = blockIdx.x;
  const int l = threadIdx.x;
  const float4* g4 = (const float4*)g;
  float4 v = g4[(size_t)c * (HD / 4) + l];
  float ax = v.x, ay = v.y, az = v.z, aw = v.w;
  #pragma unroll
  for (int k = 0; k < KNN; ++k) {
    int r = nbr[c * KNN + k];
    float4 u = g4[(size_t)r * (HD / 4) + l];
    ax += u.x; ay += u.y; az += u.z; aw += u.w;
  }
  const int o0 = off[c], o1 = o0 + cnt[c];
  for (int j = o0; j < o1; ++j) {
    int r = rev[j];
    float4 u = g4[(size_t)r * (HD / 4) + l];
    ax += u.x; ay += u.y; az += u.z; aw += u.w;
  }
  const float dc = dinv[c];
  float4 b = ((const float4*)bias)[l];
  float rx = ax * dc + b.x, ry = ay * dc + b.y, rz = az * dc + b.z, rw = aw * dc + b.w;
  if (do_relu) {
    rx = fmaxf(rx, 0.0f); ry = fmaxf(ry, 0.0f);
    rz = fmaxf(rz, 0.0f); rw = fmaxf(rw, 0.0f);
  }
  float4 o; o.x = rx; o.y = ry; o.z = rz; o.w = rw;
  ((float4*)out)[(size_t)c * (HD / 4) + l] = o;
}

// ===================== mean-pool + classifier =====================
__global__ __launch_bounds__(256) void colsum_kernel(const float* __restrict__ a, float* __restrict__ colsum)
{
  const int f = threadIdx.x;
  const int r0 = blockIdx.x * 64;
  float s = 0.0f;
  for (int r = 0; r < 64; ++r) s += a[(size_t)(r0 + r) * HD + f];
  atomicAdd(&colsum[f], s);
}

__global__ __launch_bounds__(256) void final_kernel(
    const float* __restrict__ colsum, const float* __restrict__ Wc,
    const float* __restrict__ bc, float* __restrict__ out)
{
  __shared__ float s0[256], s1[256];
  const int f = threadIdx.x;
  float bag = colsum[f] * (1.0f / (float)NN);
  s0[f] = bag * Wc[f * 2 + 0];
  s1[f] = bag * Wc[f * 2 + 1];
  __syncthreads();
  for (int st = 128; st; st >>= 1) {
    if (f < st) { s0[f] += s0[f + st]; s1[f] += s1[f + st]; }
    __syncthreads();
  }
  if (f == 0) { out[0] = s0[0] + bc[0]; out[1] = s1[0] + bc[1]; }
}

// ===================== launch =====================
extern "C" void kernel_launch(void* const* d_in, const int* in_sizes, int n_in,
                              void* d_out, int out_size, void* d_ws, size_t ws_size,
                              hipStream_t stream)
{
  const float* x   = (const float*)d_in[0];
  const float* Wp  = (const float*)d_in[1];
  const float* bp  = (const float*)d_in[2];
  const float* Wg1 = (const float*)d_in[3];
  const float* bg1 = (const float*)d_in[4];
  const float* Wg2 = (const float*)d_in[5];
  const float* bg2 = (const float*)d_in[6];
  const float* Wc  = (const float*)d_in[7];
  const float* bc  = (const float*)d_in[8];
  float* out = (float*)d_out;

  float* ws    = (float*)d_ws;
  float* h     = ws;                                // N*HD f32
  float* g     = ws + (size_t)NN * HD;              // N*HD f32 (written step 8)
  float* h1    = ws + 2 * (size_t)NN * HD;          // N*HD f32 (written step 9)
  float* agg2  = h;                                 // reuse
  float* sq    = ws + 3 * (size_t)NN * HD;          // N
  float* dinv  = sq + NN;                           // N
  float* colsum= dinv + NN;                         // HD
  int* nbr = (int*)(colsum + HD);                   // N*KNN
  int* cnt = nbr + NN * KNN;                        // N
  int* off = cnt + NN;                              // N
  int* cur = off + NN;                              // N
  int* rev = cur + NN;                              // N*KNN
  // bf16 hi/lo live in g / h1 regions (dead until steps 8/9, after kNN phase)
  ushort* hhi = (ushort*)g;                         // first 8 MB of g region
  ushort* hlo = (ushort*)h1;
  // candidate list in upper quarter of g region (offset 12.6 MB; hhi ends at 8.4 MB)
  int* cand = (int*)(g + (size_t)NN * HD * 3 / 4);  // N*NC2 ints = 2 MB

  // 1. h = relu(x @ W_proj + b_proj)
  gemm_4x8<true, true, false><<<dim3(NN / 64, HD / 128), dim3(256), 0, stream>>>(
      x, Wp, bp, nullptr, h, NN, HD, IND);
  // 2. sq[i] = ||h_i||^2 ; split h into bf16 hi/lo
  sq_kernel<<<dim3(NN / 4), dim3(256), 0, stream>>>(h, sq);
  split_kernel<<<dim3(NN * HD / 4 / 256), dim3(256), 0, stream>>>(h, hhi, hlo);
  // 3a. approx top-16 candidates per row per j-half (MFMA Gram, barrier-free K-loop)
  dist_topk_mfma<<<dim3(NN / 128, 2), dim3(512), 0, stream>>>(hhi, hlo, sq, cand);
  // 3b. exact fp32 rescore of 32 candidates -> top-5
  rescore_kernel<<<dim3(NN), dim3(128), 0, stream>>>(h, sq, cand, nbr);
  // 4. in-degree counts
  hipMemsetAsync(cnt, 0, NN * sizeof(int), stream);
  count_kernel<<<dim3((NN * KNN) / 256), dim3(256), 0, stream>>>(nbr, cnt);
  // 5. dinv
  dinv_kernel<<<dim3(NN / 256), dim3(256), 0, stream>>>(cnt, dinv);
  // 6. CSR offsets
  scan_kernel<<<dim3(1), dim3(256), 0, stream>>>(cnt, off);
  // 7. reverse adjacency
  hipMemsetAsync(cur, 0, NN * sizeof(int), stream);
  fill_rev<<<dim3((NN * KNN) / 256), dim3(256), 0, stream>>>(nbr, off, cur, rev);
  // 8. g = (h @ W_g1) * dinv[row]
  gemm_4x8<false, false, true><<<dim3(NN / 64, HD / 128), dim3(256), 0, stream>>>(
      h, Wg1, nullptr, dinv, g, NN, HD, HD);
  // 9. h1 = relu(agg(g) + b_g1)
  aggregate<<<dim3(NN), dim3(64), 0, stream>>>(g, nbr, rev, off, cnt, dinv, bg1, h1, 1);
  // 10. g = (h1 @ W_g2) * dinv[row]
  gemm_4x8<false, false, true><<<dim3(NN / 64, HD / 128), dim3(256), 0, stream>>>(
      h1, Wg2, nullptr, dinv, g, NN, HD, HD);
  // 11. agg2 = agg(g) + b_g2
  aggregate<<<dim3(NN), dim3(64), 0, stream>>>(g, nbr, rev, off, cnt, dinv, bg2, agg2, 0);
  // 12/13. mean-pool + classifier
  hipMemsetAsync(colsum, 0, HD * sizeof(float), stream);
  colsum_kernel<<<dim3(NN / 64), dim3(256), 0, stream>>>(agg2, colsum);
  final_kernel<<<dim3(1), dim3(256), 0, stream>>>(colsum, Wc, bc, out);
}